// Round 14
// baseline (2964.867 us; speedup 1.0000x reference)
//
#include <hip/hip_runtime.h>

typedef __attribute__((ext_vector_type(8))) short short8;
typedef __attribute__((ext_vector_type(4))) float f32x4;

#define NSTEP 63
#define DZ 256
#define DX 64
#define DH 1024
#define PART_FLOATS_PER_SLOT (64 * 4 * 4096)

__device__ __forceinline__ unsigned short f2bf(float f){
  unsigned u = __builtin_bit_cast(unsigned, f);
  u += 0x7fffu + ((u >> 16) & 1u);
  return (unsigned short)(u >> 16);
}
__device__ __forceinline__ float bf2f(unsigned short h){
  return __builtin_bit_cast(float, (unsigned)h << 16);
}
__device__ __forceinline__ void split_bf(float v, unsigned short& h, unsigned short& l){
  h = f2bf(v);
  l = f2bf(v - bf2f(h));
}
__device__ __forceinline__ float tanh_fast(float x){
  float e = __expf(2.0f * x);
  return 1.0f - 2.0f / (e + 1.0f);
}
__device__ __forceinline__ unsigned pk2(float a, float b){
  int r; asm("v_cvt_pk_bf16_f32 %0, %1, %2" : "=v"(r) : "v"(a), "v"(b));
  return (unsigned)r;
}
__device__ __forceinline__ void pack4(const float* v, unsigned long long& hi,
                                      unsigned long long& lo){
  unsigned h0 = pk2(v[0], v[1]), h1 = pk2(v[2], v[3]);
  float f0 = __builtin_bit_cast(float, h0 << 16);
  float f1 = __builtin_bit_cast(float, h0 & 0xffff0000u);
  float f2 = __builtin_bit_cast(float, h1 << 16);
  float f3 = __builtin_bit_cast(float, h1 & 0xffff0000u);
  unsigned l0 = pk2(v[0] - f0, v[1] - f1), l1 = pk2(v[2] - f2, v[3] - f3);
  hi = (unsigned long long)h0 | ((unsigned long long)h1 << 32);
  lo = (unsigned long long)l0 | ((unsigned long long)l1 << 32);
}

// sc0 sc1: bypass L1+L2 to device coherence point; no L2 invalidation (r7/r8).
__device__ __forceinline__ void st_sc(float* p, float v){
  asm volatile("global_store_dword %0, %1, off sc0 sc1" :: "v"(p), "v"(v) : "memory");
}

// Swizzled LDS access (XOR byte ^= (row&7)<<4).
template<int ROWB>
__device__ __forceinline__ short8 ldsA(const short* buf, int row, int k0){
  int byte = row * ROWB + k0 * 2;
  byte ^= ((row & 7) << 4);
  return *reinterpret_cast<const short8*>(reinterpret_cast<const char*>(buf) + byte);
}
template<int ROWB>
__device__ __forceinline__ void ldsW64(short* buf, int row, int col, unsigned long long v){
  int byte = row * ROWB + col * 2;
  byte ^= ((row & 7) << 4);
  *reinterpret_cast<unsigned long long*>(reinterpret_cast<char*>(buf) + byte) = v;
}
template<int ROWB>
__device__ __forceinline__ void ldsW16(short* buf, int row, int col, unsigned short v){
  int byte = row * ROWB + col * 2;
  byte ^= ((row & 7) << 4);
  *reinterpret_cast<short*>(reinterpret_cast<char*>(buf) + byte) = (short)v;
}

#define MFMA(a, b, c) __builtin_amdgcn_mfma_f32_16x16x32_bf16((a), (b), (c), 0, 0, 0)

// ---------------------------------------------------------------------------
// Reformat weights into hi/lo bf16 MFMA fragment pairs (validated r3/r5/r8).
// ---------------------------------------------------------------------------
__global__ void reformat_weights(const float* __restrict__ W1,
                                 const float* __restrict__ W2,
                                 const float* __restrict__ Wx,
                                 short* __restrict__ W1f,
                                 short* __restrict__ W2f,
                                 short* __restrict__ Wxf){
  int tid = blockIdx.x * 256 + threadIdx.x;
  if (tid < 32768){                       // W1: ks 0..7, nblk 0..63
    int lane = tid & 63, nblk = (tid >> 6) & 63, ks = tid >> 12;
    int k0 = ks * 32 + (lane >> 4) * 8, col = nblk * 16 + (lane & 15);
    short8 vh, vl;
    #pragma unroll
    for (int j = 0; j < 8; ++j){
      unsigned short h, l; split_bf(W1[(k0 + j) * DH + col], h, l);
      vh[j] = (short)h; vl[j] = (short)l;
    }
    int base = ((ks * 64 + nblk) * 2) * 64 + lane;
    reinterpret_cast<short8*>(W1f)[base]      = vh;
    reinterpret_cast<short8*>(W1f)[base + 64] = vl;
  } else if (tid < 65536){                // W2: ks 0..31, nblk 0..15
    int t = tid - 32768;
    int lane = t & 63, nblk = (t >> 6) & 15, ks = t >> 10;
    int k0 = ks * 32 + (lane >> 4) * 8, col = nblk * 16 + (lane & 15);
    short8 vh, vl;
    #pragma unroll
    for (int j = 0; j < 8; ++j){
      unsigned short h, l; split_bf(W2[(k0 + j) * DZ + col], h, l);
      vh[j] = (short)h; vl[j] = (short)l;
    }
    int base = ((ks * 16 + nblk) * 2) * 64 + lane;
    reinterpret_cast<short8*>(W2f)[base]      = vh;
    reinterpret_cast<short8*>(W2f)[base + 64] = vl;
  } else if (tid < 73728){                // Wx: ks 0..1, nblk 0..63
    int t = tid - 65536;
    int lane = t & 63, nblk = (t >> 6) & 63, ks = t >> 12;
    int k0 = ks * 32 + (lane >> 4) * 8, col = nblk * 16 + (lane & 15);
    short8 vh, vl;
    #pragma unroll
    for (int j = 0; j < 8; ++j){
      unsigned short h, l; split_bf(Wx[(k0 + j) * DH + col], h, l);
      vh[j] = (short)h; vl[j] = (short)l;
    }
    int base = ((ks * 64 + nblk) * 2) * 64 + lane;
    reinterpret_cast<short8*>(Wxf)[base]      = vh;
    reinterpret_cast<short8*>(Wxf)[base + 64] = vl;
  }
}

__global__ void init_sync(unsigned* __restrict__ ctrs){
  int t = threadIdx.x;
  if (t < 64) ctrs[t * 16] = 0;
}

// ---------------------------------------------------------------------------
// DH-split NeuralODE (r12 structure + barrier-free per-wave exchange):
// 256 WGs x 512 thr. WG (rb = wg&63, dh = wg>>6) owns rows [16rb,+16),
// DH slice [256dh,+256). Exchange: each wave drains its OWN stores
// (wave-local vmcnt), lane0 adds 1 to the group counter and spins to
// 32*(g+1) — zero barriers in the exchange (was 2). Safety: ctr>=32(g+2)
// implies every wave has stored g+1, which requires having read slot g ->
// slot g&1 reusable at stage g+2 (same invariant as r8, wave-granular).
// Arithmetic, reduce order, RK4 bit-identical to r12.
// ---------------------------------------------------------------------------
__global__ __launch_bounds__(512) void node_dh4(
    const float* __restrict__ z0, const float* __restrict__ tt,
    const float* __restrict__ x,
    const short* __restrict__ W1f, const short* __restrict__ W2f,
    const short* __restrict__ Wxf,
    const float* __restrict__ wt, const float* __restrict__ b1,
    const float* __restrict__ b2,
    float* part, unsigned* ctrs,
    float* __restrict__ out){

  const int wg   = blockIdx.x;
  const int dh   = wg >> 6;          // 0..3
  const int rb   = wg & 63;
  const int tid  = threadIdx.x;
  const int w    = tid >> 6;         // wave 0..7
  const int lane = tid & 63;
  const int l15  = lane & 15;
  const int lq   = lane >> 4;

  __shared__ __align__(16) short zsh[16 * 256], zsl[16 * 256];   // 8 KB each
  __shared__ __align__(16) short hbh[16 * 256], hbl[16 * 256];   // 8 KB each
  __shared__ __align__(16) short xbh[16 * 64], xbl[16 * 64];     // 2 KB each
  __shared__ __align__(16) float b1l[256], wtl[256];

  const short8* W1v = (const short8*)W1f;
  const short8* Wxv = (const short8*)Wxf;

  if (tid < 256){ b1l[tid] = b1[dh * 256 + tid]; wtl[tid] = wt[dh * 256 + tid]; }

  // W2 slice cache (volatile; spills to scratch at the 128-VGPR cap but the
  // scratch-stream variant measured faster than direct L2 streams — r12 1803
  // vs r8 1892). Keep as-is.
  short8 w2h[8][2], w2l[8][2];
  {
    const volatile short8* W2vv = (const volatile short8*)W2f;
    #pragma unroll
    for (int ks = 0; ks < 8; ++ks)
      #pragma unroll
      for (int n2 = 0; n2 < 2; ++n2){
        int fi = (((dh * 8 + ks) * 16 + w * 2 + n2) * 2) * 64 + lane;
        w2h[ks][n2] = W2vv[fi];
        w2l[ks][n2] = W2vv[fi + 64];
      }
  }

  // state distribution by fragment-flat index (r8): thread owns col colc,
  // rows r0r..r0r+7 interleaved as flats [8t, 8t+8)
  const int qq   = tid >> 3;
  const int l0   = (tid & 7) * 8;
  const int r0r  = (tid & 1) * 8;
  const int colc = (qq >> 2) * 16 + (l0 >> 4) * 4 + (qq & 3);
  const float b2c = b2[colc];

  float zb[8], za[8];
  #pragma unroll
  for (int e = 0; e < 8; ++e){
    zb[e] = z0[(rb * 16 + r0r + e) * DZ + colc];
    za[e] = 0.f;
    unsigned short hh, ll; split_bf(zb[e], hh, ll);
    ldsW16<512>(zsh, r0r + e, colc, hh);
    ldsW16<512>(zsl, r0r + e, colc, ll);
  }

  float* grpPart   = part + (size_t)rb * (4 * 4096);
  unsigned* myctr  = ctrs + rb * 16;
  unsigned target  = 0;

  f32x4 cx[2];

  for (int step = 0; step < NSTEP; ++step){
    const float t0 = tt[step], t1 = tt[step + 1];
    const float hs = t1 - t0;

    { // stage x[step] (hi/lo bf16, swizzled): 512 thr x 2 elems
      int e  = tid * 2;
      int xr = e >> 6, xc = e & 63;
      const float* xp = x + ((size_t)step * 1024 + rb * 16 + xr) * DX + xc;
      unsigned short h0, l0s, h1, l1;
      split_bf(xp[0], h0, l0s); split_bf(xp[1], h1, l1);
      int byte = (xr * 128 + xc * 2) ^ ((xr & 7) << 4);
      *reinterpret_cast<unsigned*>(reinterpret_cast<char*>(xbh) + byte) =
          (unsigned)h0 | ((unsigned)h1 << 16);
      *reinterpret_cast<unsigned*>(reinterpret_cast<char*>(xbl) + byte) =
          (unsigned)l0s | ((unsigned)l1 << 16);
    }
    __syncthreads();

    { // x-GEMM: cx = x@Wx slice (C-init for 4 stages), operand-swapped
      short8 axh0 = ldsA<128>(xbh, l15, lq * 8);
      short8 axh1 = ldsA<128>(xbh, l15, 32 + lq * 8);
      short8 axl0 = ldsA<128>(xbl, l15, lq * 8);
      short8 axl1 = ldsA<128>(xbl, l15, 32 + lq * 8);
      #pragma unroll
      for (int n2 = 0; n2 < 2; ++n2){
        int nblk = dh * 16 + w * 2 + n2;
        int f0 = ((     nblk) * 2) * 64 + lane;
        int f1 = ((64 + nblk) * 2) * 64 + lane;
        short8 wh0 = Wxv[f0], wl0 = Wxv[f0 + 64];
        short8 wh1 = Wxv[f1], wl1 = Wxv[f1 + 64];
        f32x4 c = {0.f, 0.f, 0.f, 0.f};
        c = MFMA(wh0, axh0, c); c = MFMA(wl0, axh0, c); c = MFMA(wh0, axl0, c);
        c = MFMA(wh1, axh1, c); c = MFMA(wl1, axh1, c); c = MFMA(wh1, axl1, c);
        cx[n2] = c;
      }
    }

    #pragma unroll 1
    for (int s = 0; s < 4; ++s){
      const float ts = (s == 0) ? t0 : ((s == 3) ? t1 : t0 + 0.5f * hs);

      // ---- GEMM1: acc = z @ W1[:, slice] + cx, 1-deep weight prefetch ----
      f32x4 acc[2] = {cx[0], cx[1]};
      {
        const int nb0 = dh * 16 + w * 2;
        short8 cwh[2], cwl[2], nwh[2], nwl[2];
        #pragma unroll
        for (int n2 = 0; n2 < 2; ++n2){
          int fi = ((nb0 + n2) * 2) * 64 + lane;
          cwh[n2] = W1v[fi]; cwl[n2] = W1v[fi + 64];
        }
        #pragma unroll 1
        for (int ks = 0; ks < 8; ++ks){
          short8 azh = ldsA<512>(zsh, l15, ks * 32 + lq * 8);
          short8 azl = ldsA<512>(zsl, l15, ks * 32 + lq * 8);
          if (ks < 7){
            #pragma unroll
            for (int n2 = 0; n2 < 2; ++n2){
              int fi = (((ks + 1) * 64 + nb0 + n2) * 2) * 64 + lane;
              nwh[n2] = W1v[fi]; nwl[n2] = W1v[fi + 64];
            }
          }
          #pragma unroll
          for (int n2 = 0; n2 < 2; ++n2){
            acc[n2] = MFMA(cwh[n2], azh, acc[n2]);
            acc[n2] = MFMA(cwl[n2], azh, acc[n2]);
            acc[n2] = MFMA(cwh[n2], azl, acc[n2]);
          }
          cwh[0] = nwh[0]; cwh[1] = nwh[1];
          cwl[0] = nwl[0]; cwl[1] = nwl[1];
        }
      }
      // epilogue: bias + tanh, pack, b64 LDS writes (local h slice)
      #pragma unroll
      for (int n2 = 0; n2 < 2; ++n2){
        int cb = w * 32 + n2 * 16 + lq * 4;
        f32x4 b1v = *reinterpret_cast<const f32x4*>(&b1l[cb]);
        f32x4 wtv = *reinterpret_cast<const f32x4*>(&wtl[cb]);
        float v[4];
        #pragma unroll
        for (int i = 0; i < 4; ++i)
          v[i] = tanh_fast(acc[n2][i] + b1v[i] + ts * wtv[i]);
        unsigned long long hi, lo;
        pack4(v, hi, lo);
        ldsW64<512>(hbh, l15, cb, hi);
        ldsW64<512>(hbl, l15, cb, lo);
      }
      __syncthreads();   // h slice ready

      // ---- GEMM2 partial: weights from cache (scratch/L2-backed) ----
      f32x4 acc2[2] = {{0.f,0.f,0.f,0.f}, {0.f,0.f,0.f,0.f}};
      #pragma unroll
      for (int ks = 0; ks < 8; ++ks){
        short8 ahh = ldsA<512>(hbh, l15, ks * 32 + lq * 8);
        short8 ahl = ldsA<512>(hbl, l15, ks * 32 + lq * 8);
        #pragma unroll
        for (int n2 = 0; n2 < 2; ++n2){
          acc2[n2] = MFMA(w2h[ks][n2], ahh, acc2[n2]);
          acc2[n2] = MFMA(w2l[ks][n2], ahh, acc2[n2]);
          acc2[n2] = MFMA(w2h[ks][n2], ahl, acc2[n2]);
        }
      }

      // ---- exchange partials: per-wave protocol, zero barriers ----
      const int g = step * 4 + s;
      float* slot = grpPart + ((g & 1) ? (size_t)PART_FLOATS_PER_SLOT : 0);
      {
        float* dst = slot + dh * 4096;
        #pragma unroll
        for (int n2 = 0; n2 < 2; ++n2)
          #pragma unroll
          for (int i = 0; i < 4; ++i){
            int flat = ((w * 2 + n2) * 4 + i) * 64 + lane;
            st_sc(dst + flat, acc2[n2][i]);
          }
      }
      asm volatile("s_waitcnt vmcnt(0)" ::: "memory");   // this wave's stores done
      target += 32;                     // 4 WGs x 8 waves per stage
      if (lane == 0){
        __hip_atomic_fetch_add(myctr, 1u, __ATOMIC_RELAXED, __HIP_MEMORY_SCOPE_AGENT);
        while (__hip_atomic_load(myctr, __ATOMIC_RELAXED, __HIP_MEMORY_SCOPE_AGENT) < target)
          __builtin_amdgcn_s_sleep(1);
      }
      // lanes reconverge here: all 32 waves' partials are at coherence point
      __builtin_amdgcn_sched_barrier(0);

      // read all 4 slots: 8 contiguous floats per thread per slot
      f32x4 v00, v01, v10, v11, v20, v21, v30, v31;
      {
        const float* pr = slot + tid * 8;
        asm volatile(
          "global_load_dwordx4 %0, %8, off sc0 sc1\n\t"
          "global_load_dwordx4 %1, %9, off sc0 sc1\n\t"
          "global_load_dwordx4 %2, %10, off sc0 sc1\n\t"
          "global_load_dwordx4 %3, %11, off sc0 sc1\n\t"
          "global_load_dwordx4 %4, %12, off sc0 sc1\n\t"
          "global_load_dwordx4 %5, %13, off sc0 sc1\n\t"
          "global_load_dwordx4 %6, %14, off sc0 sc1\n\t"
          "global_load_dwordx4 %7, %15, off sc0 sc1\n\t"
          "s_waitcnt vmcnt(0)"
          : "=&v"(v00), "=&v"(v01), "=&v"(v10), "=&v"(v11),
            "=&v"(v20), "=&v"(v21), "=&v"(v30), "=&v"(v31)
          : "v"(pr), "v"(pr + 4),
            "v"(pr + 4096), "v"(pr + 4100),
            "v"(pr + 8192), "v"(pr + 8196),
            "v"(pr + 12288), "v"(pr + 12292)
          : "memory");
      }
      __builtin_amdgcn_sched_barrier(0);

      // reduce (fixed dh order -> bit-identical across replicas) + RK4
      const float csw = (s == 0 || s == 3) ? 1.f : 2.f;
      const float dc  = (s < 2) ? 0.5f * hs : hs;
      #pragma unroll
      for (int e = 0; e < 8; ++e){
        float s0 = (e < 4) ? v00[e] : v01[e - 4];
        float s1 = (e < 4) ? v10[e] : v11[e - 4];
        float s2 = (e < 4) ? v20[e] : v21[e - 4];
        float s3 = (e < 4) ? v30[e] : v31[e - 4];
        float kv = (((s0 + s1) + s2) + s3) + b2c;
        za[e] += csw * kv;
        float zn;
        if (s < 3){
          zn = zb[e] + dc * kv;
        } else {
          zb[e] += (hs * (1.f / 6.f)) * za[e];
          za[e] = 0.f;
          zn = zb[e];
        }
        unsigned short hh, ll; split_bf(zn, hh, ll);
        ldsW16<512>(zsh, r0r + e, colc, hh);
        ldsW16<512>(zsl, r0r + e, colc, ll);
      }
      __syncthreads();                 // z ready for next stage
    }
  }

  if (dh == 0){
    #pragma unroll
    for (int e = 0; e < 8; ++e)
      out[(rb * 16 + r0r + e) * DZ + colc] = zb[e];
  }
}

// ---------------------------------------------------------------------------
// Fallback: round-2 verified fp32 VALU kernel (no workspace).
// ---------------------------------------------------------------------------
__global__ __launch_bounds__(512) void node_f32(
    const float* __restrict__ z0, const float* __restrict__ tt,
    const float* __restrict__ x,
    const float* __restrict__ W1, const float* __restrict__ Wx,
    const float* __restrict__ wt, const float* __restrict__ b1,
    const float* __restrict__ W2, const float* __restrict__ b2,
    float* __restrict__ out){
  const int wg = blockIdx.x, t = threadIdx.x;
  const int c0 = t, c1 = t + 512, c2 = t & 255, r0 = (t >> 8) * 4;
  __shared__ __align__(16) float zshm[8][260];
  __shared__ __align__(16) float hshm[8][1028];
  __shared__ __align__(16) float xshm[8][68];
  const float b1c0 = b1[c0], b1c1 = b1[c1], wtc0 = wt[c0], wtc1 = wt[c1], b2c = b2[c2];
  float zb[4], za[4];
  #pragma unroll
  for (int i = 0; i < 4; ++i){
    zb[i] = z0[(wg * 8 + r0 + i) * DZ + c2]; za[i] = 0.f; zshm[r0 + i][c2] = zb[i];
  }
  float cx0[8], cx1[8];
  for (int step = 0; step < NSTEP; ++step){
    const float t0 = tt[step], t1 = tt[step + 1], hs = t1 - t0;
    { int xr = t >> 6, xc = t & 63;
      xshm[xr][xc] = x[((size_t)step * 1024 + wg * 8 + xr) * DX + xc]; }
    __syncthreads();
    #pragma unroll
    for (int r = 0; r < 8; ++r){ cx0[r] = 0.f; cx1[r] = 0.f; }
    for (int k0 = 0; k0 < DX; k0 += 4){
      f32x4 xr4[8];
      #pragma unroll
      for (int r = 0; r < 8; ++r) xr4[r] = *(const f32x4*)&xshm[r][k0];
      float w0[4], w1[4];
      #pragma unroll
      for (int j = 0; j < 4; ++j){ w0[j] = Wx[(k0 + j) * DH + c0]; w1[j] = Wx[(k0 + j) * DH + c1]; }
      #pragma unroll
      for (int j = 0; j < 4; ++j)
        #pragma unroll
        for (int r = 0; r < 8; ++r){
          cx0[r] = fmaf(xr4[r][j], w0[j], cx0[r]); cx1[r] = fmaf(xr4[r][j], w1[j], cx1[r]); }
    }
    #pragma unroll 1
    for (int s = 0; s < 4; ++s){
      const float ts = (s == 0) ? t0 : ((s == 3) ? t1 : t0 + 0.5f * hs);
      float a0[8], a1[8];
      #pragma unroll
      for (int r = 0; r < 8; ++r){ a0[r] = cx0[r]; a1[r] = cx1[r]; }
      for (int k0 = 0; k0 < DZ; k0 += 4){
        f32x4 zr4[8];
        #pragma unroll
        for (int r = 0; r < 8; ++r) zr4[r] = *(const f32x4*)&zshm[r][k0];
        float w0[4], w1[4];
        #pragma unroll
        for (int j = 0; j < 4; ++j){ w0[j] = W1[(k0 + j) * DH + c0]; w1[j] = W1[(k0 + j) * DH + c1]; }
        #pragma unroll
        for (int j = 0; j < 4; ++j)
          #pragma unroll
          for (int r = 0; r < 8; ++r){
            a0[r] = fmaf(zr4[r][j], w0[j], a0[r]); a1[r] = fmaf(zr4[r][j], w1[j], a1[r]); }
      }
      const float bias0 = b1c0 + ts * wtc0, bias1 = b1c1 + ts * wtc1;
      #pragma unroll
      for (int r = 0; r < 8; ++r){
        hshm[r][c0] = tanh_fast(a0[r] + bias0); hshm[r][c1] = tanh_fast(a1[r] + bias1); }
      __syncthreads();
      float acc2[4] = {0.f, 0.f, 0.f, 0.f};
      for (int k0 = 0; k0 < DH; k0 += 4){
        f32x4 hr4[4];
        #pragma unroll
        for (int i = 0; i < 4; ++i) hr4[i] = *(const f32x4*)&hshm[r0 + i][k0];
        float w[4];
        #pragma unroll
        for (int j = 0; j < 4; ++j) w[j] = W2[(k0 + j) * DZ + c2];
        #pragma unroll
        for (int j = 0; j < 4; ++j)
          #pragma unroll
          for (int i = 0; i < 4; ++i) acc2[i] = fmaf(hr4[i][j], w[j], acc2[i]);
      }
      const float csw = (s == 0 || s == 3) ? 1.f : 2.f;
      const float dc = (s < 2) ? 0.5f * hs : hs;
      #pragma unroll
      for (int i = 0; i < 4; ++i){
        float kv = acc2[i] + b2c;
        za[i] += csw * kv;
        float zn;
        if (s < 3) zn = zb[i] + dc * kv;
        else { zb[i] += (hs * (1.f / 6.f)) * za[i]; za[i] = 0.f; zn = zb[i]; }
        zshm[r0 + i][c2] = zn;
      }
      __syncthreads();
    }
  }
  #pragma unroll
  for (int i = 0; i < 4; ++i) out[(wg * 8 + r0 + i) * DZ + c2] = zb[i];
}

extern "C" void kernel_launch(void* const* d_in, const int* in_sizes, int n_in,
                              void* d_out, int out_size, void* d_ws, size_t ws_size,
                              hipStream_t stream){
  const float* z0 = (const float*)d_in[0];
  const float* tt = (const float*)d_in[1];
  const float* x  = (const float*)d_in[2];
  const float* W1 = (const float*)d_in[3];
  const float* Wx = (const float*)d_in[4];
  const float* wt = (const float*)d_in[5];
  const float* b1 = (const float*)d_in[6];
  const float* W2 = (const float*)d_in[7];
  const float* b2 = (const float*)d_in[8];

  const size_t wBytes    = (size_t)(524288 + 524288 + 131072) * 2;   // 2359296
  const size_t partOff   = wBytes;
  const size_t partBytes = (size_t)2 * PART_FLOATS_PER_SLOT * 4;     // 8 MB
  const size_t ctrOff    = partOff + partBytes;
  const size_t need      = ctrOff + 64 * 16 * 4;

  if (ws_size >= need){
    short* W1f = (short*)d_ws;
    short* W2f = W1f + 524288;
    short* Wxf = W2f + 524288;
    float* part = (float*)((char*)d_ws + partOff);
    unsigned* ctrs = (unsigned*)((char*)d_ws + ctrOff);
    reformat_weights<<<288, 256, 0, stream>>>(W1, W2, Wx, W1f, W2f, Wxf);
    init_sync<<<1, 64, 0, stream>>>(ctrs);
    node_dh4<<<256, 512, 0, stream>>>(z0, tt, x, W1f, W2f, Wxf, wt, b1, b2,
                                      part, ctrs, (float*)d_out);
  } else {
    node_f32<<<128, 512, 0, stream>>>(z0, tt, x, W1, Wx, wt, b1, W2, b2,
                                      (float*)d_out);
  }
}

// Round 15
// 1786.527 us; speedup vs baseline: 1.6596x; 1.6596x over previous
//
#include <hip/hip_runtime.h>

typedef __attribute__((ext_vector_type(8))) short short8;
typedef __attribute__((ext_vector_type(4))) float f32x4;

#define NSTEP 63
#define DZ 256
#define DX 64
#define DH 1024
#define PART_FLOATS_PER_SLOT (64 * 4 * 4096)

__device__ __forceinline__ unsigned short f2bf(float f){
  unsigned u = __builtin_bit_cast(unsigned, f);
  u += 0x7fffu + ((u >> 16) & 1u);
  return (unsigned short)(u >> 16);
}
__device__ __forceinline__ float bf2f(unsigned short h){
  return __builtin_bit_cast(float, (unsigned)h << 16);
}
__device__ __forceinline__ void split_bf(float v, unsigned short& h, unsigned short& l){
  h = f2bf(v);
  l = f2bf(v - bf2f(h));
}
__device__ __forceinline__ float tanh_fast(float x){
  float e = __expf(2.0f * x);
  return 1.0f - 2.0f / (e + 1.0f);
}
__device__ __forceinline__ unsigned pk2(float a, float b){
  int r; asm("v_cvt_pk_bf16_f32 %0, %1, %2" : "=v"(r) : "v"(a), "v"(b));
  return (unsigned)r;
}
__device__ __forceinline__ void pack4(const float* v, unsigned long long& hi,
                                      unsigned long long& lo){
  unsigned h0 = pk2(v[0], v[1]), h1 = pk2(v[2], v[3]);
  float f0 = __builtin_bit_cast(float, h0 << 16);
  float f1 = __builtin_bit_cast(float, h0 & 0xffff0000u);
  float f2 = __builtin_bit_cast(float, h1 << 16);
  float f3 = __builtin_bit_cast(float, h1 & 0xffff0000u);
  unsigned l0 = pk2(v[0] - f0, v[1] - f1), l1 = pk2(v[2] - f2, v[3] - f3);
  hi = (unsigned long long)h0 | ((unsigned long long)h1 << 32);
  lo = (unsigned long long)l0 | ((unsigned long long)l1 << 32);
}

// sc0 sc1: bypass L1+L2 to device coherence point; no L2 invalidation (r7/r8).
__device__ __forceinline__ void st_sc(float* p, float v){
  asm volatile("global_store_dword %0, %1, off sc0 sc1" :: "v"(p), "v"(v) : "memory");
}

// Swizzled LDS access (XOR byte ^= (row&7)<<4).
template<int ROWB>
__device__ __forceinline__ short8 ldsA(const short* buf, int row, int k0){
  int byte = row * ROWB + k0 * 2;
  byte ^= ((row & 7) << 4);
  return *reinterpret_cast<const short8*>(reinterpret_cast<const char*>(buf) + byte);
}
template<int ROWB>
__device__ __forceinline__ void ldsW64(short* buf, int row, int col, unsigned long long v){
  int byte = row * ROWB + col * 2;
  byte ^= ((row & 7) << 4);
  *reinterpret_cast<unsigned long long*>(reinterpret_cast<char*>(buf) + byte) = v;
}
template<int ROWB>
__device__ __forceinline__ void ldsW16(short* buf, int row, int col, unsigned short v){
  int byte = row * ROWB + col * 2;
  byte ^= ((row & 7) << 4);
  *reinterpret_cast<short*>(reinterpret_cast<char*>(buf) + byte) = (short)v;
}

#define MFMA(a, b, c) __builtin_amdgcn_mfma_f32_16x16x32_bf16((a), (b), (c), 0, 0, 0)

// ---------------------------------------------------------------------------
// Reformat weights into hi/lo bf16 MFMA fragment pairs (validated r3/r5/r8).
// ---------------------------------------------------------------------------
__global__ void reformat_weights(const float* __restrict__ W1,
                                 const float* __restrict__ W2,
                                 const float* __restrict__ Wx,
                                 short* __restrict__ W1f,
                                 short* __restrict__ W2f,
                                 short* __restrict__ Wxf){
  int tid = blockIdx.x * 256 + threadIdx.x;
  if (tid < 32768){                       // W1: ks 0..7, nblk 0..63
    int lane = tid & 63, nblk = (tid >> 6) & 63, ks = tid >> 12;
    int k0 = ks * 32 + (lane >> 4) * 8, col = nblk * 16 + (lane & 15);
    short8 vh, vl;
    #pragma unroll
    for (int j = 0; j < 8; ++j){
      unsigned short h, l; split_bf(W1[(k0 + j) * DH + col], h, l);
      vh[j] = (short)h; vl[j] = (short)l;
    }
    int base = ((ks * 64 + nblk) * 2) * 64 + lane;
    reinterpret_cast<short8*>(W1f)[base]      = vh;
    reinterpret_cast<short8*>(W1f)[base + 64] = vl;
  } else if (tid < 65536){                // W2: ks 0..31, nblk 0..15
    int t = tid - 32768;
    int lane = t & 63, nblk = (t >> 6) & 15, ks = t >> 10;
    int k0 = ks * 32 + (lane >> 4) * 8, col = nblk * 16 + (lane & 15);
    short8 vh, vl;
    #pragma unroll
    for (int j = 0; j < 8; ++j){
      unsigned short h, l; split_bf(W2[(k0 + j) * DZ + col], h, l);
      vh[j] = (short)h; vl[j] = (short)l;
    }
    int base = ((ks * 16 + nblk) * 2) * 64 + lane;
    reinterpret_cast<short8*>(W2f)[base]      = vh;
    reinterpret_cast<short8*>(W2f)[base + 64] = vl;
  } else if (tid < 73728){                // Wx: ks 0..1, nblk 0..63
    int t = tid - 65536;
    int lane = t & 63, nblk = (t >> 6) & 63, ks = t >> 12;
    int k0 = ks * 32 + (lane >> 4) * 8, col = nblk * 16 + (lane & 15);
    short8 vh, vl;
    #pragma unroll
    for (int j = 0; j < 8; ++j){
      unsigned short h, l; split_bf(Wx[(k0 + j) * DH + col], h, l);
      vh[j] = (short)h; vl[j] = (short)l;
    }
    int base = ((ks * 64 + nblk) * 2) * 64 + lane;
    reinterpret_cast<short8*>(Wxf)[base]      = vh;
    reinterpret_cast<short8*>(Wxf)[base + 64] = vl;
  }
}

__global__ void init_sync(unsigned* __restrict__ ctrs){
  int t = threadIdx.x;
  if (t < 64) ctrs[t * 16] = 0;
}

// ---------------------------------------------------------------------------
// DH-split NeuralODE (r12 configuration — best measured: 1803 us, absmax
// 0.03125): 256 WGs x 512 thr. WG (rb = wg&63, dh = wg>>6) owns batch rows
// [16rb,+16), DH slice [256dh,+256). Block-wide exchange protocol (r8-proven:
// vmcnt(0) + syncthreads + tid0 counter + syncthreads). W2 "cache" retained
// as in r12 (spills to scratch at the 128-VGPR pin, but r12 measured faster
// than r8's direct stream). Do NOT use per-wave counters (r14: -64%), do NOT
// use waves_per_eu (r13: neutral + outliers), do NOT asm-prefetch weights
// (r11: spill corruption).
// ---------------------------------------------------------------------------
__global__ __launch_bounds__(512) void node_dh4(
    const float* __restrict__ z0, const float* __restrict__ tt,
    const float* __restrict__ x,
    const short* __restrict__ W1f, const short* __restrict__ W2f,
    const short* __restrict__ Wxf,
    const float* __restrict__ wt, const float* __restrict__ b1,
    const float* __restrict__ b2,
    float* part, unsigned* ctrs,
    float* __restrict__ out){

  const int wg   = blockIdx.x;
  const int dh   = wg >> 6;          // 0..3
  const int rb   = wg & 63;
  const int tid  = threadIdx.x;
  const int w    = tid >> 6;         // wave 0..7
  const int lane = tid & 63;
  const int l15  = lane & 15;
  const int lq   = lane >> 4;

  __shared__ __align__(16) short zsh[16 * 256], zsl[16 * 256];   // 8 KB each
  __shared__ __align__(16) short hbh[16 * 256], hbl[16 * 256];   // 8 KB each
  __shared__ __align__(16) short xbh[16 * 64], xbl[16 * 64];     // 2 KB each
  __shared__ __align__(16) float b1l[256], wtl[256];

  const short8* W1v = (const short8*)W1f;
  const short8* Wxv = (const short8*)Wxf;

  if (tid < 256){ b1l[tid] = b1[dh * 256 + tid]; wtl[tid] = wt[dh * 256 + tid]; }

  // W2 slice cache (volatile; scratch-backed at the 128-VGPR cap — measured
  // faster than direct per-stage L2 streaming in r12 vs r8).
  short8 w2h[8][2], w2l[8][2];
  {
    const volatile short8* W2vv = (const volatile short8*)W2f;
    #pragma unroll
    for (int ks = 0; ks < 8; ++ks)
      #pragma unroll
      for (int n2 = 0; n2 < 2; ++n2){
        int fi = (((dh * 8 + ks) * 16 + w * 2 + n2) * 2) * 64 + lane;
        w2h[ks][n2] = W2vv[fi];
        w2l[ks][n2] = W2vv[fi + 64];
      }
  }

  // state distribution by fragment-flat index (r8): thread owns col colc,
  // rows r0r..r0r+7 interleaved as flats [8t, 8t+8)
  const int qq   = tid >> 3;
  const int l0   = (tid & 7) * 8;
  const int r0r  = (tid & 1) * 8;
  const int colc = (qq >> 2) * 16 + (l0 >> 4) * 4 + (qq & 3);
  const float b2c = b2[colc];

  float zb[8], za[8];
  #pragma unroll
  for (int e = 0; e < 8; ++e){
    zb[e] = z0[(rb * 16 + r0r + e) * DZ + colc];
    za[e] = 0.f;
    unsigned short hh, ll; split_bf(zb[e], hh, ll);
    ldsW16<512>(zsh, r0r + e, colc, hh);
    ldsW16<512>(zsl, r0r + e, colc, ll);
  }

  float* grpPart   = part + (size_t)rb * (4 * 4096);
  unsigned* myctr  = ctrs + rb * 16;
  unsigned target  = 0;

  f32x4 cx[2];

  for (int step = 0; step < NSTEP; ++step){
    const float t0 = tt[step], t1 = tt[step + 1];
    const float hs = t1 - t0;

    { // stage x[step] (hi/lo bf16, swizzled): 512 thr x 2 elems
      int e  = tid * 2;
      int xr = e >> 6, xc = e & 63;
      const float* xp = x + ((size_t)step * 1024 + rb * 16 + xr) * DX + xc;
      unsigned short h0, l0s, h1, l1;
      split_bf(xp[0], h0, l0s); split_bf(xp[1], h1, l1);
      int byte = (xr * 128 + xc * 2) ^ ((xr & 7) << 4);
      *reinterpret_cast<unsigned*>(reinterpret_cast<char*>(xbh) + byte) =
          (unsigned)h0 | ((unsigned)h1 << 16);
      *reinterpret_cast<unsigned*>(reinterpret_cast<char*>(xbl) + byte) =
          (unsigned)l0s | ((unsigned)l1 << 16);
    }
    __syncthreads();

    { // x-GEMM: cx = x@Wx slice (C-init for 4 stages), operand-swapped
      short8 axh0 = ldsA<128>(xbh, l15, lq * 8);
      short8 axh1 = ldsA<128>(xbh, l15, 32 + lq * 8);
      short8 axl0 = ldsA<128>(xbl, l15, lq * 8);
      short8 axl1 = ldsA<128>(xbl, l15, 32 + lq * 8);
      #pragma unroll
      for (int n2 = 0; n2 < 2; ++n2){
        int nblk = dh * 16 + w * 2 + n2;
        int f0 = ((     nblk) * 2) * 64 + lane;
        int f1 = ((64 + nblk) * 2) * 64 + lane;
        short8 wh0 = Wxv[f0], wl0 = Wxv[f0 + 64];
        short8 wh1 = Wxv[f1], wl1 = Wxv[f1 + 64];
        f32x4 c = {0.f, 0.f, 0.f, 0.f};
        c = MFMA(wh0, axh0, c); c = MFMA(wl0, axh0, c); c = MFMA(wh0, axl0, c);
        c = MFMA(wh1, axh1, c); c = MFMA(wl1, axh1, c); c = MFMA(wh1, axl1, c);
        cx[n2] = c;
      }
    }

    #pragma unroll 1
    for (int s = 0; s < 4; ++s){
      const float ts = (s == 0) ? t0 : ((s == 3) ? t1 : t0 + 0.5f * hs);

      // ---- GEMM1: acc = z @ W1[:, slice] + cx, 1-deep weight prefetch ----
      f32x4 acc[2] = {cx[0], cx[1]};
      {
        const int nb0 = dh * 16 + w * 2;
        short8 cwh[2], cwl[2], nwh[2], nwl[2];
        #pragma unroll
        for (int n2 = 0; n2 < 2; ++n2){
          int fi = ((nb0 + n2) * 2) * 64 + lane;
          cwh[n2] = W1v[fi]; cwl[n2] = W1v[fi + 64];
        }
        #pragma unroll 1
        for (int ks = 0; ks < 8; ++ks){
          short8 azh = ldsA<512>(zsh, l15, ks * 32 + lq * 8);
          short8 azl = ldsA<512>(zsl, l15, ks * 32 + lq * 8);
          if (ks < 7){
            #pragma unroll
            for (int n2 = 0; n2 < 2; ++n2){
              int fi = (((ks + 1) * 64 + nb0 + n2) * 2) * 64 + lane;
              nwh[n2] = W1v[fi]; nwl[n2] = W1v[fi + 64];
            }
          }
          #pragma unroll
          for (int n2 = 0; n2 < 2; ++n2){
            acc[n2] = MFMA(cwh[n2], azh, acc[n2]);
            acc[n2] = MFMA(cwl[n2], azh, acc[n2]);
            acc[n2] = MFMA(cwh[n2], azl, acc[n2]);
          }
          cwh[0] = nwh[0]; cwh[1] = nwh[1];
          cwl[0] = nwl[0]; cwl[1] = nwl[1];
        }
      }
      // epilogue: bias + tanh, pack, b64 LDS writes (local h slice)
      #pragma unroll
      for (int n2 = 0; n2 < 2; ++n2){
        int cb = w * 32 + n2 * 16 + lq * 4;
        f32x4 b1v = *reinterpret_cast<const f32x4*>(&b1l[cb]);
        f32x4 wtv = *reinterpret_cast<const f32x4*>(&wtl[cb]);
        float v[4];
        #pragma unroll
        for (int i = 0; i < 4; ++i)
          v[i] = tanh_fast(acc[n2][i] + b1v[i] + ts * wtv[i]);
        unsigned long long hi, lo;
        pack4(v, hi, lo);
        ldsW64<512>(hbh, l15, cb, hi);
        ldsW64<512>(hbl, l15, cb, lo);
      }
      __syncthreads();   // h slice ready

      // ---- GEMM2 partial: weights from the cache ----
      f32x4 acc2[2] = {{0.f,0.f,0.f,0.f}, {0.f,0.f,0.f,0.f}};
      #pragma unroll
      for (int ks = 0; ks < 8; ++ks){
        short8 ahh = ldsA<512>(hbh, l15, ks * 32 + lq * 8);
        short8 ahl = ldsA<512>(hbl, l15, ks * 32 + lq * 8);
        #pragma unroll
        for (int n2 = 0; n2 < 2; ++n2){
          acc2[n2] = MFMA(w2h[ks][n2], ahh, acc2[n2]);
          acc2[n2] = MFMA(w2l[ks][n2], ahh, acc2[n2]);
          acc2[n2] = MFMA(w2h[ks][n2], ahl, acc2[n2]);
        }
      }

      // ---- exchange partials (fragment-flat layout, coalesced, sc0 sc1) ----
      const int g = step * 4 + s;
      float* slot = grpPart + ((g & 1) ? (size_t)PART_FLOATS_PER_SLOT : 0);
      {
        float* dst = slot + dh * 4096;
        #pragma unroll
        for (int n2 = 0; n2 < 2; ++n2)
          #pragma unroll
          for (int i = 0; i < 4; ++i){
            int flat = ((w * 2 + n2) * 4 + i) * 64 + lane;
            st_sc(dst + flat, acc2[n2][i]);
          }
      }
      asm volatile("s_waitcnt vmcnt(0)" ::: "memory");
      __syncthreads();                 // all stores at coherence point
      target += 4;
      if (tid == 0){
        __hip_atomic_fetch_add(myctr, 1u, __ATOMIC_RELAXED, __HIP_MEMORY_SCOPE_AGENT);
        while (__hip_atomic_load(myctr, __ATOMIC_RELAXED, __HIP_MEMORY_SCOPE_AGENT) < target)
          __builtin_amdgcn_s_sleep(1);
      }
      __syncthreads();                 // all 4 partials visible

      // read all 4 slots: 8 contiguous floats per thread per slot
      f32x4 v00, v01, v10, v11, v20, v21, v30, v31;
      {
        const float* pr = slot + tid * 8;
        asm volatile(
          "global_load_dwordx4 %0, %8, off sc0 sc1\n\t"
          "global_load_dwordx4 %1, %9, off sc0 sc1\n\t"
          "global_load_dwordx4 %2, %10, off sc0 sc1\n\t"
          "global_load_dwordx4 %3, %11, off sc0 sc1\n\t"
          "global_load_dwordx4 %4, %12, off sc0 sc1\n\t"
          "global_load_dwordx4 %5, %13, off sc0 sc1\n\t"
          "global_load_dwordx4 %6, %14, off sc0 sc1\n\t"
          "global_load_dwordx4 %7, %15, off sc0 sc1\n\t"
          "s_waitcnt vmcnt(0)"
          : "=&v"(v00), "=&v"(v01), "=&v"(v10), "=&v"(v11),
            "=&v"(v20), "=&v"(v21), "=&v"(v30), "=&v"(v31)
          : "v"(pr), "v"(pr + 4),
            "v"(pr + 4096), "v"(pr + 4100),
            "v"(pr + 8192), "v"(pr + 8196),
            "v"(pr + 12288), "v"(pr + 12292)
          : "memory");
      }
      __builtin_amdgcn_sched_barrier(0);

      // reduce (fixed dh order -> bit-identical across replicas) + RK4
      const float csw = (s == 0 || s == 3) ? 1.f : 2.f;
      const float dc  = (s < 2) ? 0.5f * hs : hs;
      #pragma unroll
      for (int e = 0; e < 8; ++e){
        float s0 = (e < 4) ? v00[e] : v01[e - 4];
        float s1 = (e < 4) ? v10[e] : v11[e - 4];
        float s2 = (e < 4) ? v20[e] : v21[e - 4];
        float s3 = (e < 4) ? v30[e] : v31[e - 4];
        float kv = (((s0 + s1) + s2) + s3) + b2c;
        za[e] += csw * kv;
        float zn;
        if (s < 3){
          zn = zb[e] + dc * kv;
        } else {
          zb[e] += (hs * (1.f / 6.f)) * za[e];
          za[e] = 0.f;
          zn = zb[e];
        }
        unsigned short hh, ll; split_bf(zn, hh, ll);
        ldsW16<512>(zsh, r0r + e, colc, hh);
        ldsW16<512>(zsl, r0r + e, colc, ll);
      }
      __syncthreads();                 // z ready for next stage
    }
  }

  if (dh == 0){
    #pragma unroll
    for (int e = 0; e < 8; ++e)
      out[(rb * 16 + r0r + e) * DZ + colc] = zb[e];
  }
}

// ---------------------------------------------------------------------------
// Fallback: round-2 verified fp32 VALU kernel (no workspace).
// ---------------------------------------------------------------------------
__global__ __launch_bounds__(512) void node_f32(
    const float* __restrict__ z0, const float* __restrict__ tt,
    const float* __restrict__ x,
    const float* __restrict__ W1, const float* __restrict__ Wx,
    const float* __restrict__ wt, const float* __restrict__ b1,
    const float* __restrict__ W2, const float* __restrict__ b2,
    float* __restrict__ out){
  const int wg = blockIdx.x, t = threadIdx.x;
  const int c0 = t, c1 = t + 512, c2 = t & 255, r0 = (t >> 8) * 4;
  __shared__ __align__(16) float zshm[8][260];
  __shared__ __align__(16) float hshm[8][1028];
  __shared__ __align__(16) float xshm[8][68];
  const float b1c0 = b1[c0], b1c1 = b1[c1], wtc0 = wt[c0], wtc1 = wt[c1], b2c = b2[c2];
  float zb[4], za[4];
  #pragma unroll
  for (int i = 0; i < 4; ++i){
    zb[i] = z0[(wg * 8 + r0 + i) * DZ + c2]; za[i] = 0.f; zshm[r0 + i][c2] = zb[i];
  }
  float cx0[8], cx1[8];
  for (int step = 0; step < NSTEP; ++step){
    const float t0 = tt[step], t1 = tt[step + 1], hs = t1 - t0;
    { int xr = t >> 6, xc = t & 63;
      xshm[xr][xc] = x[((size_t)step * 1024 + wg * 8 + xr) * DX + xc]; }
    __syncthreads();
    #pragma unroll
    for (int r = 0; r < 8; ++r){ cx0[r] = 0.f; cx1[r] = 0.f; }
    for (int k0 = 0; k0 < DX; k0 += 4){
      f32x4 xr4[8];
      #pragma unroll
      for (int r = 0; r < 8; ++r) xr4[r] = *(const f32x4*)&xshm[r][k0];
      float w0[4], w1[4];
      #pragma unroll
      for (int j = 0; j < 4; ++j){ w0[j] = Wx[(k0 + j) * DH + c0]; w1[j] = Wx[(k0 + j) * DH + c1]; }
      #pragma unroll
      for (int j = 0; j < 4; ++j)
        #pragma unroll
        for (int r = 0; r < 8; ++r){
          cx0[r] = fmaf(xr4[r][j], w0[j], cx0[r]); cx1[r] = fmaf(xr4[r][j], w1[j], cx1[r]); }
    }
    #pragma unroll 1
    for (int s = 0; s < 4; ++s){
      const float ts = (s == 0) ? t0 : ((s == 3) ? t1 : t0 + 0.5f * hs);
      float a0[8], a1[8];
      #pragma unroll
      for (int r = 0; r < 8; ++r){ a0[r] = cx0[r]; a1[r] = cx1[r]; }
      for (int k0 = 0; k0 < DZ; k0 += 4){
        f32x4 zr4[8];
        #pragma unroll
        for (int r = 0; r < 8; ++r) zr4[r] = *(const f32x4*)&zshm[r][k0];
        float w0[4], w1[4];
        #pragma unroll
        for (int j = 0; j < 4; ++j){ w0[j] = W1[(k0 + j) * DH + c0]; w1[j] = W1[(k0 + j) * DH + c1]; }
        #pragma unroll
        for (int j = 0; j < 4; ++j)
          #pragma unroll
          for (int r = 0; r < 8; ++r){
            a0[r] = fmaf(zr4[r][j], w0[j], a0[r]); a1[r] = fmaf(zr4[r][j], w1[j], a1[r]); }
      }
      const float bias0 = b1c0 + ts * wtc0, bias1 = b1c1 + ts * wtc1;
      #pragma unroll
      for (int r = 0; r < 8; ++r){
        hshm[r][c0] = tanh_fast(a0[r] + bias0); hshm[r][c1] = tanh_fast(a1[r] + bias1); }
      __syncthreads();
      float acc2[4] = {0.f, 0.f, 0.f, 0.f};
      for (int k0 = 0; k0 < DH; k0 += 4){
        f32x4 hr4[4];
        #pragma unroll
        for (int i = 0; i < 4; ++i) hr4[i] = *(const f32x4*)&hshm[r0 + i][k0];
        float w[4];
        #pragma unroll
        for (int j = 0; j < 4; ++j) w[j] = W2[(k0 + j) * DZ + c2];
        #pragma unroll
        for (int j = 0; j < 4; ++j)
          #pragma unroll
          for (int i = 0; i < 4; ++i) acc2[i] = fmaf(hr4[i][j], w[j], acc2[i]);
      }
      const float csw = (s == 0 || s == 3) ? 1.f : 2.f;
      const float dc = (s < 2) ? 0.5f * hs : hs;
      #pragma unroll
      for (int i = 0; i < 4; ++i){
        float kv = acc2[i] + b2c;
        za[i] += csw * kv;
        float zn;
        if (s < 3) zn = zb[i] + dc * kv;
        else { zb[i] += (hs * (1.f / 6.f)) * za[i]; za[i] = 0.f; zn = zb[i]; }
        zshm[r0 + i][c2] = zn;
      }
      __syncthreads();
    }
  }
  #pragma unroll
  for (int i = 0; i < 4; ++i) out[(wg * 8 + r0 + i) * DZ + c2] = zb[i];
}

extern "C" void kernel_launch(void* const* d_in, const int* in_sizes, int n_in,
                              void* d_out, int out_size, void* d_ws, size_t ws_size,
                              hipStream_t stream){
  const float* z0 = (const float*)d_in[0];
  const float* tt = (const float*)d_in[1];
  const float* x  = (const float*)d_in[2];
  const float* W1 = (const float*)d_in[3];
  const float* Wx = (const float*)d_in[4];
  const float* wt = (const float*)d_in[5];
  const float* b1 = (const float*)d_in[6];
  const float* W2 = (const float*)d_in[7];
  const float* b2 = (const float*)d_in[8];

  const size_t wBytes    = (size_t)(524288 + 524288 + 131072) * 2;   // 2359296
  const size_t partOff   = wBytes;
  const size_t partBytes = (size_t)2 * PART_FLOATS_PER_SLOT * 4;     // 8 MB
  const size_t ctrOff    = partOff + partBytes;
  const size_t need      = ctrOff + 64 * 16 * 4;

  if (ws_size >= need){
    short* W1f = (short*)d_ws;
    short* W2f = W1f + 524288;
    short* Wxf = W2f + 524288;
    float* part = (float*)((char*)d_ws + partOff);
    unsigned* ctrs = (unsigned*)((char*)d_ws + ctrOff);
    reformat_weights<<<288, 256, 0, stream>>>(W1, W2, Wx, W1f, W2f, Wxf);
    init_sync<<<1, 64, 0, stream>>>(ctrs);
    node_dh4<<<256, 512, 0, stream>>>(z0, tt, x, W1f, W2f, Wxf, wt, b1, b2,
                                      part, ctrs, (float*)d_out);
  } else {
    node_f32<<<128, 512, 0, stream>>>(z0, tt, x, W1, Wx, wt, b1, W2, b2,
                                      (float*)d_out);
  }
}